// Round 1
// baseline (1360.239 us; speedup 1.0000x reference)
//
#include <hip/hip_runtime.h>
#include <stdint.h>

#define GN 50000
#define GE 50000
#define GKK 16
#define DD 256
#define INDIM 240

// ---------- scalar reductions: max(visit_times), sum(visit_times) in f64 ----------
__global__ __launch_bounds__(256) void k_reduce(const float* __restrict__ t, int n,
                                                unsigned int* maxbits, double* sum) {
  int i0 = blockIdx.x * blockDim.x + threadIdx.x;
  int stride = gridDim.x * blockDim.x;
  float m = 0.f; double s = 0.0;
  for (int i = i0; i < n; i += stride) { float v = t[i]; m = fmaxf(m, v); s += (double)v; }
  for (int o = 32; o; o >>= 1) { m = fmaxf(m, __shfl_xor(m, o)); s += __shfl_xor(s, o); }
  if ((threadIdx.x & 63) == 0) { atomicMax(maxbits, __float_as_uint(m)); atomicAdd(sum, s); }
}

// ---------- w[e] = exp(-(max-t)/365); tn[j] = mean_t*Wt[j]+bt[j] ----------
__global__ __launch_bounds__(256) void k_w(const float* __restrict__ t,
                                           const unsigned int* maxbits, const double* sum,
                                           const float* __restrict__ Wt, const float* __restrict__ bt,
                                           float* __restrict__ w, float* __restrict__ tn) {
  int i = blockIdx.x * blockDim.x + threadIdx.x;
  float maxt = __uint_as_float(*maxbits);
  if (i < GE) w[i] = expf((t[i] - maxt) * (1.0f / 365.0f));
  if (blockIdx.x == 0 && threadIdx.x < 16) {
    float mean = (float)(*sum / (double)GE);
    tn[threadIdx.x] = mean * Wt[threadIdx.x] + bt[threadIdx.x];
  }
}

// ---------- CSR build ----------
__global__ __launch_bounds__(256) void k_count(const int* __restrict__ edges, int* __restrict__ cnt) {
  int i = blockIdx.x * 256 + threadIdx.x;
  if (i < GE * GKK) atomicAdd(&cnt[edges[i]], 1);
}

__global__ __launch_bounds__(256) void k_scan(const int* __restrict__ cnt, int* __restrict__ off) {
  __shared__ int part[256];
  int t = threadIdx.x;
  const int chunk = (GN + 255) / 256;
  int beg = t * chunk, end = beg + chunk; if (end > GN) end = GN; if (beg > GN) beg = GN;
  int s = 0;
  for (int i = beg; i < end; i++) s += cnt[i];
  part[t] = s; __syncthreads();
  for (int d = 1; d < 256; d <<= 1) {
    int v = (t >= d) ? part[t - d] : 0;
    __syncthreads();
    part[t] += v;
    __syncthreads();
  }
  int base = (t == 0) ? 0 : part[t - 1];
  for (int i = beg; i < end; i++) { off[i] = base; base += cnt[i]; }
  if (t == 255) off[GN] = base;
}

__global__ __launch_bounds__(256) void k_fill(const int* __restrict__ edges, const int* __restrict__ off,
                                              int* __restrict__ cur, int* __restrict__ csr) {
  int i = blockIdx.x * 256 + threadIdx.x;
  if (i < GE * GKK) {
    int n = edges[i];
    int p = atomicAdd(&cur[n], 1);
    csr[off[n] + p] = i >> 4;  // edge id (K=16)
  }
}

// ---------- dv_isqrt[n] = dv>0 ? 1/sqrt(dv) : 0, dv = sum of w over incident slots ----------
__global__ __launch_bounds__(256) void k_dv(const int* __restrict__ off, const int* __restrict__ csr,
                                            const float* __restrict__ w, float* __restrict__ dvis) {
  int n = blockIdx.x * 256 + threadIdx.x;
  if (n >= GN) return;
  float dv = 0.f;
  int e0 = off[n], e1 = off[n + 1];
  for (int j = e0; j < e1; j++) dv += w[csr[j]];
  dvis[n] = dv > 0.f ? 1.0f / sqrtf(fmaxf(dv, 1e-12f)) : 0.f;
}

// ---------- h0 = concat(X, tnode) ----------
__global__ __launch_bounds__(256) void k_h0(const float* __restrict__ X, const float* __restrict__ tn,
                                            float* __restrict__ h) {
  int wid = threadIdx.x >> 6, lane = threadIdx.x & 63;
  int n = blockIdx.x * 4 + wid;
  if (n >= GN) return;
  float4 v;
  if (lane < 60) v = *(const float4*)&X[(size_t)n * INDIM + (lane << 2)];
  else           v = *(const float4*)&tn[(lane - 60) << 2];
  *(float4*)&h[(size_t)n * DD + (lane << 2)] = v;
}

// ---------- tiled SGEMM: out[r,:] = (A[r,:] @ W + bias) * dvis[r] ----------
// BM=64 rows, BN=256 (full), BK=32
__global__ __launch_bounds__(256) void k_gemm(const float* __restrict__ A, const float* __restrict__ W,
                                              const float* __restrict__ bias, const float* __restrict__ dvis,
                                              float* __restrict__ out) {
  __shared__ float As[64][32];
  __shared__ float Ws[32][DD];
  int t = threadIdx.x;
  int lane = t & 63;
  int wid = t >> 6;
  int row0 = blockIdx.x * 64;

  float acc[16][4];
#pragma unroll
  for (int i = 0; i < 16; i++)
#pragma unroll
    for (int j = 0; j < 4; j++) acc[i][j] = 0.f;

  for (int k0 = 0; k0 < DD; k0 += 32) {
    // A tile: 64x32 floats = 512 float4 / 256 threads = 2 each
#pragma unroll
    for (int i = 0; i < 2; i++) {
      int g = t + i * 256;
      int r = g >> 3, c4 = g & 7;
      int gr = row0 + r;
      float4 v = make_float4(0.f, 0.f, 0.f, 0.f);
      if (gr < GN) v = *(const float4*)&A[(size_t)gr * DD + k0 + (c4 << 2)];
      *(float4*)&As[r][c4 << 2] = v;
    }
    // W tile: 32x256 floats = 2048 float4 / 256 threads = 8 each
#pragma unroll
    for (int i = 0; i < 8; i++) {
      int g = t + i * 256;
      int r = g >> 6, c4 = g & 63;
      *(float4*)&Ws[r][c4 << 2] = *(const float4*)&W[(size_t)(k0 + r) * DD + (c4 << 2)];
    }
    __syncthreads();
#pragma unroll
    for (int kk4 = 0; kk4 < 8; kk4++) {
      float4 w0 = *(const float4*)&Ws[kk4 * 4 + 0][lane << 2];
      float4 w1 = *(const float4*)&Ws[kk4 * 4 + 1][lane << 2];
      float4 w2 = *(const float4*)&Ws[kk4 * 4 + 2][lane << 2];
      float4 w3 = *(const float4*)&Ws[kk4 * 4 + 3][lane << 2];
#pragma unroll
      for (int i = 0; i < 16; i++) {
        float4 a = *(const float4*)&As[(wid << 4) + i][kk4 << 2];
        acc[i][0] = fmaf(a.x, w0.x, fmaf(a.y, w1.x, fmaf(a.z, w2.x, fmaf(a.w, w3.x, acc[i][0]))));
        acc[i][1] = fmaf(a.x, w0.y, fmaf(a.y, w1.y, fmaf(a.z, w2.y, fmaf(a.w, w3.y, acc[i][1]))));
        acc[i][2] = fmaf(a.x, w0.z, fmaf(a.y, w1.z, fmaf(a.z, w2.z, fmaf(a.w, w3.z, acc[i][2]))));
        acc[i][3] = fmaf(a.x, w0.w, fmaf(a.y, w1.w, fmaf(a.z, w2.w, fmaf(a.w, w3.w, acc[i][3]))));
      }
    }
    __syncthreads();
  }
  float4 bb = *(const float4*)&bias[lane << 2];
#pragma unroll
  for (int i = 0; i < 16; i++) {
    int gr = row0 + (wid << 4) + i;
    if (gr < GN) {
      float s = dvis[gr];
      float4 o;
      o.x = (acc[i][0] + bb.x) * s;
      o.y = (acc[i][1] + bb.y) * s;
      o.z = (acc[i][2] + bb.z) * s;
      o.w = (acc[i][3] + bb.w) * s;
      *(float4*)&out[(size_t)gr * DD + (lane << 2)] = o;
    }
  }
}

// ---------- per-edge: msg[e] = w[e] * mean_k xs[edges[e,k]] ----------
__global__ __launch_bounds__(256) void k_edge_msg(const float* __restrict__ xs, const int* __restrict__ edges,
                                                  const float* __restrict__ w, float* __restrict__ msg) {
  int wid = threadIdx.x >> 6, lane = threadIdx.x & 63;
  int e = blockIdx.x * 4 + wid;
  if (e >= GE) return;
  float4 s = make_float4(0.f, 0.f, 0.f, 0.f);
#pragma unroll
  for (int k = 0; k < GKK; k++) {
    int nd = edges[e * GKK + k];
    float4 v = *(const float4*)&xs[(size_t)nd * DD + (lane << 2)];
    s.x += v.x; s.y += v.y; s.z += v.z; s.w += v.w;
  }
  float f = w[e] * (1.0f / GKK);
  s.x *= f; s.y *= f; s.z *= f; s.w *= f;
  *(float4*)&msg[(size_t)e * DD + (lane << 2)] = s;
}

// ---------- per-node: out[n] = dvis[n] * sum_{e in inc(n)} msg[e] ----------
__global__ __launch_bounds__(256) void k_node_smooth(const float* __restrict__ msg, const int* __restrict__ off,
                                                     const int* __restrict__ csr, const float* __restrict__ dvis,
                                                     float* __restrict__ out) {
  int wid = threadIdx.x >> 6, lane = threadIdx.x & 63;
  int n = blockIdx.x * 4 + wid;
  if (n >= GN) return;
  int e0 = off[n], e1 = off[n + 1];
  float4 s = make_float4(0.f, 0.f, 0.f, 0.f);
  for (int j = e0; j < e1; j++) {
    int e = csr[j];
    float4 v = *(const float4*)&msg[(size_t)e * DD + (lane << 2)];
    s.x += v.x; s.y += v.y; s.z += v.z; s.w += v.w;
  }
  float sc = dvis[n];
  s.x *= sc; s.y *= sc; s.z *= sc; s.w *= sc;
  *(float4*)&out[(size_t)n * DD + (lane << 2)] = s;
}

// ---------- per-edge attention: ef = mean_k h[..]; a = sigmoid(ef.aw+ab); msg = a*ef ----------
__global__ __launch_bounds__(256) void k_edge_att(const float* __restrict__ h, const int* __restrict__ edges,
                                                  const float* __restrict__ aw, const float* __restrict__ ab,
                                                  float* __restrict__ msg) {
  int wid = threadIdx.x >> 6, lane = threadIdx.x & 63;
  int e = blockIdx.x * 4 + wid;
  if (e >= GE) return;
  float4 s = make_float4(0.f, 0.f, 0.f, 0.f);
#pragma unroll
  for (int k = 0; k < GKK; k++) {
    int nd = edges[e * GKK + k];
    float4 v = *(const float4*)&h[(size_t)nd * DD + (lane << 2)];
    s.x += v.x; s.y += v.y; s.z += v.z; s.w += v.w;
  }
  s.x *= (1.0f / GKK); s.y *= (1.0f / GKK); s.z *= (1.0f / GKK); s.w *= (1.0f / GKK);
  float4 a4 = *(const float4*)&aw[lane << 2];
  float d = s.x * a4.x + s.y * a4.y + s.z * a4.z + s.w * a4.w;
  for (int o = 32; o; o >>= 1) d += __shfl_xor(d, o);
  float a = 1.0f / (1.0f + expf(-(d + ab[0])));
  s.x *= a; s.y *= a; s.z *= a; s.w *= a;
  *(float4*)&msg[(size_t)e * DD + (lane << 2)] = s;
}

// ---------- per-node: out[n] = leaky_relu( sum msg / max(cnt,1), 0.2 ) ----------
__global__ __launch_bounds__(256) void k_node_att(const float* __restrict__ msg, const int* __restrict__ off,
                                                  const int* __restrict__ csr, const int* __restrict__ cnt,
                                                  float* __restrict__ out) {
  int wid = threadIdx.x >> 6, lane = threadIdx.x & 63;
  int n = blockIdx.x * 4 + wid;
  if (n >= GN) return;
  int e0 = off[n], e1 = off[n + 1];
  float4 s = make_float4(0.f, 0.f, 0.f, 0.f);
  for (int j = e0; j < e1; j++) {
    int e = csr[j];
    float4 v = *(const float4*)&msg[(size_t)e * DD + (lane << 2)];
    s.x += v.x; s.y += v.y; s.z += v.z; s.w += v.w;
  }
  float inv = 1.0f / fmaxf((float)cnt[n], 1.0f);
  s.x *= inv; s.y *= inv; s.z *= inv; s.w *= inv;
  float4 o;
  o.x = s.x > 0.f ? s.x : 0.2f * s.x;
  o.y = s.y > 0.f ? s.y : 0.2f * s.y;
  o.z = s.z > 0.f ? s.z : 0.2f * s.z;
  o.w = s.w > 0.f ? s.w : 0.2f * s.w;
  *(float4*)&out[(size_t)n * DD + (lane << 2)] = o;
}

extern "C" void kernel_launch(void* const* d_in, const int* in_sizes, int n_in,
                              void* d_out, int out_size, void* d_ws, size_t ws_size,
                              hipStream_t stream) {
  (void)in_sizes; (void)n_in; (void)out_size; (void)ws_size;
  const float* X    = (const float*)d_in[0];
  const int*   edges= (const int*)d_in[1];
  const float* vt   = (const float*)d_in[2];
  const float* Wt   = (const float*)d_in[3];
  const float* bt   = (const float*)d_in[4];
  const float* th1  = (const float*)d_in[5];
  const float* b1   = (const float*)d_in[6];
  const float* aw1  = (const float*)d_in[7];
  const float* ab1  = (const float*)d_in[8];
  const float* th2  = (const float*)d_in[9];
  const float* b2   = (const float*)d_in[10];
  const float* aw2  = (const float*)d_in[11];
  const float* ab2  = (const float*)d_in[12];
  float* outp = (float*)d_out;

  char* p = (char*)d_ws;
  float* P0  = (float*)p; p += (size_t)GN * DD * 4;
  float* P1  = (float*)p; p += (size_t)GN * DD * 4;
  float* w   = (float*)p; p += (size_t)GE * 4;
  float* dvis= (float*)p; p += (size_t)GN * 4;
  float* tn  = (float*)p; p += 16 * 4;
  int* cnt   = (int*)p;   p += (size_t)GN * 4;
  int* off   = (int*)p;   p += (size_t)(GN + 1) * 4;
  int* cur   = (int*)p;   p += (size_t)GN * 4;
  int* csr   = (int*)p;   p += (size_t)GE * GKK * 4;
  p = (char*)(((uintptr_t)p + 15) & ~(uintptr_t)15);
  double* dsum = (double*)p;              // 8 bytes
  unsigned int* mbits = (unsigned int*)(p + 8);

  hipMemsetAsync(cnt, 0, (size_t)GN * 4, stream);
  hipMemsetAsync(cur, 0, (size_t)GN * 4, stream);
  hipMemsetAsync(dsum, 0, 16, stream);

  k_reduce<<<196, 256, 0, stream>>>(vt, GE, mbits, dsum);
  k_w<<<196, 256, 0, stream>>>(vt, mbits, dsum, Wt, bt, w, tn);
  k_count<<<3125, 256, 0, stream>>>(edges, cnt);
  k_scan<<<1, 256, 0, stream>>>(cnt, off);
  k_fill<<<3125, 256, 0, stream>>>(edges, off, cur, csr);
  k_dv<<<196, 256, 0, stream>>>(off, csr, w, dvis);
  k_h0<<<12500, 256, 0, stream>>>(X, tn, P0);

  // ---- layer 1:  P0 -> P1 -> out -> P0 -> P1 -> out ----
  k_gemm<<<782, 256, 0, stream>>>(P0, th1, b1, dvis, P1);
  k_edge_msg<<<12500, 256, 0, stream>>>(P1, edges, w, outp);
  k_node_smooth<<<12500, 256, 0, stream>>>(outp, off, csr, dvis, P0);
  k_edge_att<<<12500, 256, 0, stream>>>(P0, edges, aw1, ab1, P1);
  k_node_att<<<12500, 256, 0, stream>>>(P1, off, csr, cnt, outp);

  // ---- layer 2:  out -> P0 -> P1 -> P0 -> P1 -> out ----
  k_gemm<<<782, 256, 0, stream>>>(outp, th2, b2, dvis, P0);
  k_edge_msg<<<12500, 256, 0, stream>>>(P0, edges, w, P1);
  k_node_smooth<<<12500, 256, 0, stream>>>(P1, off, csr, dvis, P0);
  k_edge_att<<<12500, 256, 0, stream>>>(P0, edges, aw2, ab2, P1);
  k_node_att<<<12500, 256, 0, stream>>>(P1, off, csr, cnt, outp);
}

// Round 4
// 1241.814 us; speedup vs baseline: 1.0954x; 1.0954x over previous
//
#include <hip/hip_runtime.h>
#include <stdint.h>

#define GN 50000
#define GE 50000
#define GKK 16
#define DD 256
#define INDIM 240

typedef _Float16 f16;
typedef _Float16 half4 __attribute__((ext_vector_type(4)));

__device__ inline float4 ld_h4(const f16* p) {
  half4 v = *(const half4*)p;
  return make_float4((float)v.x, (float)v.y, (float)v.z, (float)v.w);
}
__device__ inline void st_h4(f16* p, float4 v) {
  half4 h;
  h.x = (f16)v.x; h.y = (f16)v.y; h.z = (f16)v.z; h.w = (f16)v.w;
  *(half4*)p = h;
}

// ---------- scalar reductions: max(visit_times), sum(visit_times) in f64 ----------
__global__ __launch_bounds__(256) void k_reduce(const float* __restrict__ t, int n,
                                                unsigned int* maxbits, double* sum) {
  int i0 = blockIdx.x * blockDim.x + threadIdx.x;
  int stride = gridDim.x * blockDim.x;
  float m = 0.f; double s = 0.0;
  for (int i = i0; i < n; i += stride) { float v = t[i]; m = fmaxf(m, v); s += (double)v; }
  for (int o = 32; o; o >>= 1) { m = fmaxf(m, __shfl_xor(m, o)); s += __shfl_xor(s, o); }
  if ((threadIdx.x & 63) == 0) { atomicMax(maxbits, __float_as_uint(m)); atomicAdd(sum, s); }
}

// ---------- w[e] = exp(-(max-t)/365); tn[j] = mean_t*Wt[j]+bt[j] ----------
__global__ __launch_bounds__(256) void k_w(const float* __restrict__ t,
                                           const unsigned int* maxbits, const double* sum,
                                           const float* __restrict__ Wt, const float* __restrict__ bt,
                                           float* __restrict__ w, float* __restrict__ tn) {
  int i = blockIdx.x * blockDim.x + threadIdx.x;
  float maxt = __uint_as_float(*maxbits);
  if (i < GE) w[i] = expf((t[i] - maxt) * (1.0f / 365.0f));
  if (blockIdx.x == 0 && threadIdx.x < 16) {
    float mean = (float)(*sum / (double)GE);
    tn[threadIdx.x] = mean * Wt[threadIdx.x] + bt[threadIdx.x];
  }
}

// ---------- CSR build ----------
__global__ __launch_bounds__(256) void k_count(const int* __restrict__ edges, int* __restrict__ cnt) {
  int i = blockIdx.x * 256 + threadIdx.x;
  if (i < GE * GKK) atomicAdd(&cnt[edges[i]], 1);
}

__global__ __launch_bounds__(256) void k_scan(const int* __restrict__ cnt, int* __restrict__ off) {
  __shared__ int part[256];
  int t = threadIdx.x;
  const int chunk = (GN + 255) / 256;
  int beg = t * chunk, end = beg + chunk; if (end > GN) end = GN; if (beg > GN) beg = GN;
  int s = 0;
  for (int i = beg; i < end; i++) s += cnt[i];
  part[t] = s; __syncthreads();
  for (int d = 1; d < 256; d <<= 1) {
    int v = (t >= d) ? part[t - d] : 0;
    __syncthreads();
    part[t] += v;
    __syncthreads();
  }
  int base = (t == 0) ? 0 : part[t - 1];
  for (int i = beg; i < end; i++) { off[i] = base; base += cnt[i]; }
  if (t == 255) off[GN] = base;
}

__global__ __launch_bounds__(256) void k_fill(const int* __restrict__ edges, const int* __restrict__ off,
                                              int* __restrict__ cur, int* __restrict__ csr) {
  int i = blockIdx.x * 256 + threadIdx.x;
  if (i < GE * GKK) {
    int n = edges[i];
    int p = atomicAdd(&cur[n], 1);
    csr[off[n] + p] = i >> 4;  // edge id (K=16)
  }
}

// ---------- dv_isqrt ----------
__global__ __launch_bounds__(256) void k_dv(const int* __restrict__ off, const int* __restrict__ csr,
                                            const float* __restrict__ w, float* __restrict__ dvis) {
  int n = blockIdx.x * 256 + threadIdx.x;
  if (n >= GN) return;
  float dv = 0.f;
  int e0 = off[n], e1 = off[n + 1];
  for (int j = e0; j < e1; j++) dv += w[csr[j]];
  dvis[n] = dv > 0.f ? 1.0f / sqrtf(fmaxf(dv, 1e-12f)) : 0.f;
}

// ---------- h0 = concat(X, tnode) ----------
__global__ __launch_bounds__(256) void k_h0(const float* __restrict__ X, const float* __restrict__ tn,
                                            float* __restrict__ h) {
  int wid = threadIdx.x >> 6, lane = threadIdx.x & 63;
  int n = blockIdx.x * 4 + wid;
  if (n >= GN) return;
  float4 v;
  if (lane < 60) v = *(const float4*)&X[(size_t)n * INDIM + (lane << 2)];
  else           v = *(const float4*)&tn[(lane - 60) << 2];
  *(float4*)&h[(size_t)n * DD + (lane << 2)] = v;
}

// ---------- tiled SGEMM (identical to R1): out[r,:] = (A[r,:] @ W + bias) * dvis[r] ----------
__global__ __launch_bounds__(256) void k_gemm(const float* __restrict__ A, const float* __restrict__ W,
                                              const float* __restrict__ bias, const float* __restrict__ dvis,
                                              float* __restrict__ out) {
  __shared__ float As[64][32];
  __shared__ float Ws[32][DD];
  int t = threadIdx.x;
  int lane = t & 63;
  int wid = t >> 6;
  int row0 = blockIdx.x * 64;

  float acc[16][4];
#pragma unroll
  for (int i = 0; i < 16; i++)
#pragma unroll
    for (int j = 0; j < 4; j++) acc[i][j] = 0.f;

  for (int k0 = 0; k0 < DD; k0 += 32) {
#pragma unroll
    for (int i = 0; i < 2; i++) {
      int g = t + i * 256;
      int r = g >> 3, c4 = g & 7;
      int gr = row0 + r;
      float4 v = make_float4(0.f, 0.f, 0.f, 0.f);
      if (gr < GN) v = *(const float4*)&A[(size_t)gr * DD + k0 + (c4 << 2)];
      *(float4*)&As[r][c4 << 2] = v;
    }
#pragma unroll
    for (int i = 0; i < 8; i++) {
      int g = t + i * 256;
      int r = g >> 6, c4 = g & 63;
      *(float4*)&Ws[r][c4 << 2] = *(const float4*)&W[(size_t)(k0 + r) * DD + (c4 << 2)];
    }
    __syncthreads();
#pragma unroll
    for (int kk4 = 0; kk4 < 8; kk4++) {
      float4 w0 = *(const float4*)&Ws[kk4 * 4 + 0][lane << 2];
      float4 w1 = *(const float4*)&Ws[kk4 * 4 + 1][lane << 2];
      float4 w2 = *(const float4*)&Ws[kk4 * 4 + 2][lane << 2];
      float4 w3 = *(const float4*)&Ws[kk4 * 4 + 3][lane << 2];
#pragma unroll
      for (int i = 0; i < 16; i++) {
        float4 a = *(const float4*)&As[(wid << 4) + i][kk4 << 2];
        acc[i][0] = fmaf(a.x, w0.x, fmaf(a.y, w1.x, fmaf(a.z, w2.x, fmaf(a.w, w3.x, acc[i][0]))));
        acc[i][1] = fmaf(a.x, w0.y, fmaf(a.y, w1.y, fmaf(a.z, w2.y, fmaf(a.w, w3.y, acc[i][1]))));
        acc[i][2] = fmaf(a.x, w0.z, fmaf(a.y, w1.z, fmaf(a.z, w2.z, fmaf(a.w, w3.z, acc[i][2]))));
        acc[i][3] = fmaf(a.x, w0.w, fmaf(a.y, w1.w, fmaf(a.z, w2.w, fmaf(a.w, w3.w, acc[i][3]))));
      }
    }
    __syncthreads();
  }
  float4 bb = *(const float4*)&bias[lane << 2];
#pragma unroll
  for (int i = 0; i < 16; i++) {
    int gr = row0 + (wid << 4) + i;
    if (gr < GN) {
      float s = dvis[gr];
      float4 o;
      o.x = (acc[i][0] + bb.x) * s;
      o.y = (acc[i][1] + bb.y) * s;
      o.z = (acc[i][2] + bb.z) * s;
      o.w = (acc[i][3] + bb.w) * s;
      *(float4*)&out[(size_t)gr * DD + (lane << 2)] = o;
    }
  }
}

// ---------- per-edge: msg[e] = w[e] * mean_k xs[edges[e,k]]  (f32 in, f16 out) ----------
__global__ __launch_bounds__(256) void k_edge_msg(const float* __restrict__ xs, const int* __restrict__ edges,
                                                  const float* __restrict__ w, f16* __restrict__ msg) {
  int wid = threadIdx.x >> 6, lane = threadIdx.x & 63;
  int e = blockIdx.x * 4 + wid;
  if (e >= GE) return;
  float4 s = make_float4(0.f, 0.f, 0.f, 0.f);
#pragma unroll
  for (int k = 0; k < GKK; k++) {
    int nd = edges[e * GKK + k];
    float4 v = *(const float4*)&xs[(size_t)nd * DD + (lane << 2)];
    s.x += v.x; s.y += v.y; s.z += v.z; s.w += v.w;
  }
  float f = w[e] * (1.0f / GKK);
  s.x *= f; s.y *= f; s.z *= f; s.w *= f;
  st_h4(&msg[(size_t)e * DD + (lane << 2)], s);
}

// ---------- per-node: out[n] = dvis[n] * sum msg[e]  (f16 in, f32 out) ----------
__global__ __launch_bounds__(256) void k_node_smooth(const f16* __restrict__ msg, const int* __restrict__ off,
                                                     const int* __restrict__ csr, const float* __restrict__ dvis,
                                                     float* __restrict__ out) {
  int wid = threadIdx.x >> 6, lane = threadIdx.x & 63;
  int n = blockIdx.x * 4 + wid;
  if (n >= GN) return;
  int e0 = off[n], e1 = off[n + 1];
  float4 s = make_float4(0.f, 0.f, 0.f, 0.f);
  for (int j = e0; j < e1; j++) {
    int e = csr[j];
    float4 v = ld_h4(&msg[(size_t)e * DD + (lane << 2)]);
    s.x += v.x; s.y += v.y; s.z += v.z; s.w += v.w;
  }
  float sc = dvis[n];
  s.x *= sc; s.y *= sc; s.z *= sc; s.w *= sc;
  *(float4*)&out[(size_t)n * DD + (lane << 2)] = s;
}

// ---------- per-edge attention (f32 in, f16 out) ----------
__global__ __launch_bounds__(256) void k_edge_att(const float* __restrict__ h, const int* __restrict__ edges,
                                                  const float* __restrict__ aw, const float* __restrict__ ab,
                                                  f16* __restrict__ msg) {
  int wid = threadIdx.x >> 6, lane = threadIdx.x & 63;
  int e = blockIdx.x * 4 + wid;
  if (e >= GE) return;
  float4 s = make_float4(0.f, 0.f, 0.f, 0.f);
#pragma unroll
  for (int k = 0; k < GKK; k++) {
    int nd = edges[e * GKK + k];
    float4 v = *(const float4*)&h[(size_t)nd * DD + (lane << 2)];
    s.x += v.x; s.y += v.y; s.z += v.z; s.w += v.w;
  }
  s.x *= (1.0f / GKK); s.y *= (1.0f / GKK); s.z *= (1.0f / GKK); s.w *= (1.0f / GKK);
  float4 a4 = *(const float4*)&aw[lane << 2];
  float d = s.x * a4.x + s.y * a4.y + s.z * a4.z + s.w * a4.w;
  for (int o = 32; o; o >>= 1) d += __shfl_xor(d, o);
  float a = 1.0f / (1.0f + expf(-(d + ab[0])));
  s.x *= a; s.y *= a; s.z *= a; s.w *= a;
  st_h4(&msg[(size_t)e * DD + (lane << 2)], s);
}

// ---------- per-node: out[n] = leaky_relu( sum msg / max(cnt,1), 0.2 )  (f16 in, f32 out) ----------
__global__ __launch_bounds__(256) void k_node_att(const f16* __restrict__ msg, const int* __restrict__ off,
                                                  const int* __restrict__ csr, const int* __restrict__ cnt,
                                                  float* __restrict__ out) {
  int wid = threadIdx.x >> 6, lane = threadIdx.x & 63;
  int n = blockIdx.x * 4 + wid;
  if (n >= GN) return;
  int e0 = off[n], e1 = off[n + 1];
  float4 s = make_float4(0.f, 0.f, 0.f, 0.f);
  for (int j = e0; j < e1; j++) {
    int e = csr[j];
    float4 v = ld_h4(&msg[(size_t)e * DD + (lane << 2)]);
    s.x += v.x; s.y += v.y; s.z += v.z; s.w += v.w;
  }
  float inv = 1.0f / fmaxf((float)cnt[n], 1.0f);
  s.x *= inv; s.y *= inv; s.z *= inv; s.w *= inv;
  float4 o;
  o.x = s.x > 0.f ? s.x : 0.2f * s.x;
  o.y = s.y > 0.f ? s.y : 0.2f * s.y;
  o.z = s.z > 0.f ? s.z : 0.2f * s.z;
  o.w = s.w > 0.f ? s.w : 0.2f * s.w;
  *(float4*)&out[(size_t)n * DD + (lane << 2)] = o;
}

extern "C" void kernel_launch(void* const* d_in, const int* in_sizes, int n_in,
                              void* d_out, int out_size, void* d_ws, size_t ws_size,
                              hipStream_t stream) {
  (void)in_sizes; (void)n_in; (void)out_size; (void)ws_size;
  const float* X    = (const float*)d_in[0];
  const int*   edges= (const int*)d_in[1];
  const float* vt   = (const float*)d_in[2];
  const float* Wt   = (const float*)d_in[3];
  const float* bt   = (const float*)d_in[4];
  const float* th1  = (const float*)d_in[5];
  const float* b1   = (const float*)d_in[6];
  const float* aw1  = (const float*)d_in[7];
  const float* ab1  = (const float*)d_in[8];
  const float* th2  = (const float*)d_in[9];
  const float* b2   = (const float*)d_in[10];
  const float* aw2  = (const float*)d_in[11];
  const float* ab2  = (const float*)d_in[12];
  float* outp = (float*)d_out;

  // ---- workspace layout: byte-identical to R1 (proven) ----
  char* p = (char*)d_ws;
  float* P0  = (float*)p; p += (size_t)GN * DD * 4;
  float* P1  = (float*)p; p += (size_t)GN * DD * 4;
  float* w   = (float*)p; p += (size_t)GE * 4;
  float* dvis= (float*)p; p += (size_t)GN * 4;
  float* tn  = (float*)p; p += 16 * 4;
  int* cnt   = (int*)p;   p += (size_t)GN * 4;
  int* off   = (int*)p;   p += (size_t)(GN + 1) * 4;
  int* cur   = (int*)p;   p += (size_t)GN * 4;
  int* csr   = (int*)p;   p += (size_t)GE * GKK * 4;
  p = (char*)(((uintptr_t)p + 15) & ~(uintptr_t)15);
  double* dsum = (double*)p;
  unsigned int* mbits = (unsigned int*)(p + 8);

  // fp16 msg views carved inside existing f32 buffers (25.6MB fits in 51.2MB)
  f16* M_out = (f16*)outp;  // lower half of d_out
  f16* M_p1  = (f16*)P1;    // lower half of P1

  hipMemsetAsync(cnt, 0, (size_t)GN * 4, stream);
  hipMemsetAsync(cur, 0, (size_t)GN * 4, stream);
  hipMemsetAsync(dsum, 0, 16, stream);

  k_reduce<<<196, 256, 0, stream>>>(vt, GE, mbits, dsum);
  k_w<<<196, 256, 0, stream>>>(vt, mbits, dsum, Wt, bt, w, tn);
  k_count<<<3125, 256, 0, stream>>>(edges, cnt);
  k_scan<<<1, 256, 0, stream>>>(cnt, off);
  k_fill<<<3125, 256, 0, stream>>>(edges, off, cur, csr);
  k_dv<<<196, 256, 0, stream>>>(off, csr, w, dvis);
  k_h0<<<12500, 256, 0, stream>>>(X, tn, P0);

  // ---- layer 1 ----
  k_gemm<<<782, 256, 0, stream>>>(P0, th1, b1, dvis, P1);              // P0 -> P1 (f32 g1)
  k_edge_msg<<<12500, 256, 0, stream>>>(P1, edges, w, M_out);          // g1 -> M@outp (f16)
  k_node_smooth<<<12500, 256, 0, stream>>>(M_out, off, csr, dvis, P0); // M -> P0 (f32 h1s; h0 dead)
  k_edge_att<<<12500, 256, 0, stream>>>(P0, edges, aw1, ab1, M_p1);    // h1s -> M@P1 (f16; g1 dead)
  k_node_att<<<12500, 256, 0, stream>>>(M_p1, off, csr, cnt, outp);    // M@P1 -> outp (f32 h1; M@outp dead)

  // ---- layer 2 ----
  k_gemm<<<782, 256, 0, stream>>>(outp, th2, b2, dvis, P0);            // outp -> P0 (f32 g2; h1s dead)
  k_edge_msg<<<12500, 256, 0, stream>>>(P0, edges, w, M_p1);           // g2 -> M@P1 (f16; old M dead)
  k_node_smooth<<<12500, 256, 0, stream>>>(M_p1, off, csr, dvis, P0);  // M@P1 -> P0 (f32 h2s; g2 dead)
  k_edge_att<<<12500, 256, 0, stream>>>(P0, edges, aw2, ab2, M_p1);    // h2s -> M@P1 (f16)
  k_node_att<<<12500, 256, 0, stream>>>(M_p1, off, csr, cnt, outp);    // M@P1 -> outp (f32 final; h1 dead)
}

// Round 5
// 1138.865 us; speedup vs baseline: 1.1944x; 1.0904x over previous
//
#include <hip/hip_runtime.h>
#include <stdint.h>

#define GN 50000
#define GE 50000
#define GKK 16
#define DD 256
#define INDIM 240

typedef _Float16 f16;
typedef _Float16 half4 __attribute__((ext_vector_type(4)));

__device__ inline float4 ld_h4(const f16* p) {
  half4 v = *(const half4*)p;
  return make_float4((float)v.x, (float)v.y, (float)v.z, (float)v.w);
}
// clamped store: insurance against f16 overflow -> inf -> NaN
__device__ inline void st_h4c(f16* p, float4 v) {
  half4 h;
  h.x = (f16)fminf(fmaxf(v.x, -60000.f), 60000.f);
  h.y = (f16)fminf(fmaxf(v.y, -60000.f), 60000.f);
  h.z = (f16)fminf(fmaxf(v.z, -60000.f), 60000.f);
  h.w = (f16)fminf(fmaxf(v.w, -60000.f), 60000.f);
  *(half4*)p = h;
}

// ---------- scalar reductions: max(visit_times), sum(visit_times) in f64 ----------
__global__ __launch_bounds__(256) void k_reduce(const float* __restrict__ t, int n,
                                                unsigned int* maxbits, double* sum) {
  int i0 = blockIdx.x * blockDim.x + threadIdx.x;
  int stride = gridDim.x * blockDim.x;
  float m = 0.f; double s = 0.0;
  for (int i = i0; i < n; i += stride) { float v = t[i]; m = fmaxf(m, v); s += (double)v; }
  for (int o = 32; o; o >>= 1) { m = fmaxf(m, __shfl_xor(m, o)); s += __shfl_xor(s, o); }
  if ((threadIdx.x & 63) == 0) { atomicMax(maxbits, __float_as_uint(m)); atomicAdd(sum, s); }
}

// ---------- w[e] = exp(-(max-t)/365); tn[j] = mean_t*Wt[j]+bt[j] ----------
__global__ __launch_bounds__(256) void k_w(const float* __restrict__ t,
                                           const unsigned int* maxbits, const double* sum,
                                           const float* __restrict__ Wt, const float* __restrict__ bt,
                                           float* __restrict__ w, float* __restrict__ tn) {
  int i = blockIdx.x * blockDim.x + threadIdx.x;
  float maxt = __uint_as_float(*maxbits);
  if (i < GE) w[i] = expf((t[i] - maxt) * (1.0f / 365.0f));
  if (blockIdx.x == 0 && threadIdx.x < 16) {
    float mean = (float)(*sum / (double)GE);
    tn[threadIdx.x] = mean * Wt[threadIdx.x] + bt[threadIdx.x];
  }
}

// ---------- CSR build ----------
__global__ __launch_bounds__(256) void k_count(const int* __restrict__ edges, int* __restrict__ cnt) {
  int i = blockIdx.x * 256 + threadIdx.x;
  if (i < GE * GKK) atomicAdd(&cnt[edges[i]], 1);
}

__global__ __launch_bounds__(256) void k_scan(const int* __restrict__ cnt, int* __restrict__ off) {
  __shared__ int part[256];
  int t = threadIdx.x;
  const int chunk = (GN + 255) / 256;
  int beg = t * chunk, end = beg + chunk; if (end > GN) end = GN; if (beg > GN) beg = GN;
  int s = 0;
  for (int i = beg; i < end; i++) s += cnt[i];
  part[t] = s; __syncthreads();
  for (int d = 1; d < 256; d <<= 1) {
    int v = (t >= d) ? part[t - d] : 0;
    __syncthreads();
    part[t] += v;
    __syncthreads();
  }
  int base = (t == 0) ? 0 : part[t - 1];
  for (int i = beg; i < end; i++) { off[i] = base; base += cnt[i]; }
  if (t == 255) off[GN] = base;
}

__global__ __launch_bounds__(256) void k_fill(const int* __restrict__ edges, const int* __restrict__ off,
                                              int* __restrict__ cur, int* __restrict__ csr) {
  int i = blockIdx.x * 256 + threadIdx.x;
  if (i < GE * GKK) {
    int n = edges[i];
    int p = atomicAdd(&cur[n], 1);
    csr[off[n] + p] = i >> 4;  // edge id (K=16)
  }
}

// ---------- dv_isqrt ----------
__global__ __launch_bounds__(256) void k_dv(const int* __restrict__ off, const int* __restrict__ csr,
                                            const float* __restrict__ w, float* __restrict__ dvis) {
  int n = blockIdx.x * 256 + threadIdx.x;
  if (n >= GN) return;
  float dv = 0.f;
  int e0 = off[n], e1 = off[n + 1];
  for (int j = e0; j < e1; j++) dv += w[csr[j]];
  dvis[n] = dv > 0.f ? 1.0f / sqrtf(fmaxf(dv, 1e-12f)) : 0.f;
}

// ---------- h0 = concat(X, tnode) ----------
__global__ __launch_bounds__(256) void k_h0(const float* __restrict__ X, const float* __restrict__ tn,
                                            float* __restrict__ h) {
  int wid = threadIdx.x >> 6, lane = threadIdx.x & 63;
  int n = blockIdx.x * 4 + wid;
  if (n >= GN) return;
  float4 v;
  if (lane < 60) v = *(const float4*)&X[(size_t)n * INDIM + (lane << 2)];
  else           v = *(const float4*)&tn[(lane - 60) << 2];
  *(float4*)&h[(size_t)n * DD + (lane << 2)] = v;
}

// ---------- tiled SGEMM (R1 internals): out[r,:] = (A[r,:] @ W + bias) * dvis[r], f16 out ----------
__global__ __launch_bounds__(256) void k_gemm(const float* __restrict__ A, const float* __restrict__ W,
                                              const float* __restrict__ bias, const float* __restrict__ dvis,
                                              f16* __restrict__ out) {
  __shared__ float As[64][32];
  __shared__ float Ws[32][DD];
  int t = threadIdx.x;
  int lane = t & 63;
  int wid = t >> 6;
  int row0 = blockIdx.x * 64;

  float acc[16][4];
#pragma unroll
  for (int i = 0; i < 16; i++)
#pragma unroll
    for (int j = 0; j < 4; j++) acc[i][j] = 0.f;

  for (int k0 = 0; k0 < DD; k0 += 32) {
#pragma unroll
    for (int i = 0; i < 2; i++) {
      int g = t + i * 256;
      int r = g >> 3, c4 = g & 7;
      int gr = row0 + r;
      float4 v = make_float4(0.f, 0.f, 0.f, 0.f);
      if (gr < GN) v = *(const float4*)&A[(size_t)gr * DD + k0 + (c4 << 2)];
      *(float4*)&As[r][c4 << 2] = v;
    }
#pragma unroll
    for (int i = 0; i < 8; i++) {
      int g = t + i * 256;
      int r = g >> 6, c4 = g & 63;
      *(float4*)&Ws[r][c4 << 2] = *(const float4*)&W[(size_t)(k0 + r) * DD + (c4 << 2)];
    }
    __syncthreads();
#pragma unroll
    for (int kk4 = 0; kk4 < 8; kk4++) {
      float4 w0 = *(const float4*)&Ws[kk4 * 4 + 0][lane << 2];
      float4 w1 = *(const float4*)&Ws[kk4 * 4 + 1][lane << 2];
      float4 w2 = *(const float4*)&Ws[kk4 * 4 + 2][lane << 2];
      float4 w3 = *(const float4*)&Ws[kk4 * 4 + 3][lane << 2];
#pragma unroll
      for (int i = 0; i < 16; i++) {
        float4 a = *(const float4*)&As[(wid << 4) + i][kk4 << 2];
        acc[i][0] = fmaf(a.x, w0.x, fmaf(a.y, w1.x, fmaf(a.z, w2.x, fmaf(a.w, w3.x, acc[i][0]))));
        acc[i][1] = fmaf(a.x, w0.y, fmaf(a.y, w1.y, fmaf(a.z, w2.y, fmaf(a.w, w3.y, acc[i][1]))));
        acc[i][2] = fmaf(a.x, w0.z, fmaf(a.y, w1.z, fmaf(a.z, w2.z, fmaf(a.w, w3.z, acc[i][2]))));
        acc[i][3] = fmaf(a.x, w0.w, fmaf(a.y, w1.w, fmaf(a.z, w2.w, fmaf(a.w, w3.w, acc[i][3]))));
      }
    }
    __syncthreads();
  }
  float4 bb = *(const float4*)&bias[lane << 2];
#pragma unroll
  for (int i = 0; i < 16; i++) {
    int gr = row0 + (wid << 4) + i;
    if (gr < GN) {
      float s = dvis[gr];
      float4 o;
      o.x = (acc[i][0] + bb.x) * s;
      o.y = (acc[i][1] + bb.y) * s;
      o.z = (acc[i][2] + bb.z) * s;
      o.w = (acc[i][3] + bb.w) * s;
      st_h4c(&out[(size_t)gr * DD + (lane << 2)], o);
    }
  }
}

// ---------- per-edge: msg[e] = w[e] * mean_k xs[edges[e,k]]  (f16 in, f16 out) ----------
__global__ __launch_bounds__(256) void k_edge_msg(const f16* __restrict__ xs, const int* __restrict__ edges,
                                                  const float* __restrict__ w, f16* __restrict__ msg) {
  int wid = threadIdx.x >> 6, lane = threadIdx.x & 63;
  int e = blockIdx.x * 4 + wid;
  if (e >= GE) return;
  float4 s = make_float4(0.f, 0.f, 0.f, 0.f);
#pragma unroll
  for (int k = 0; k < GKK; k++) {
    int nd = edges[e * GKK + k];
    float4 v = ld_h4(&xs[(size_t)nd * DD + (lane << 2)]);
    s.x += v.x; s.y += v.y; s.z += v.z; s.w += v.w;
  }
  float f = w[e] * (1.0f / GKK);
  s.x *= f; s.y *= f; s.z *= f; s.w *= f;
  st_h4c(&msg[(size_t)e * DD + (lane << 2)], s);
}

// ---------- per-node: h[n] = dvis[n] * sum msg[e]  (f16 in, f16 out) ----------
__global__ __launch_bounds__(256) void k_node_smooth(const f16* __restrict__ msg, const int* __restrict__ off,
                                                     const int* __restrict__ csr, const float* __restrict__ dvis,
                                                     f16* __restrict__ out) {
  int wid = threadIdx.x >> 6, lane = threadIdx.x & 63;
  int n = blockIdx.x * 4 + wid;
  if (n >= GN) return;
  int e0 = off[n], e1 = off[n + 1];
  float4 s = make_float4(0.f, 0.f, 0.f, 0.f);
  for (int j = e0; j < e1; j++) {
    int e = csr[j];
    float4 v = ld_h4(&msg[(size_t)e * DD + (lane << 2)]);
    s.x += v.x; s.y += v.y; s.z += v.z; s.w += v.w;
  }
  float sc = dvis[n];
  s.x *= sc; s.y *= sc; s.z *= sc; s.w *= sc;
  st_h4c(&out[(size_t)n * DD + (lane << 2)], s);
}

// ---------- per-edge attention (f16 in, f16 out) ----------
__global__ __launch_bounds__(256) void k_edge_att(const f16* __restrict__ h, const int* __restrict__ edges,
                                                  const float* __restrict__ aw, const float* __restrict__ ab,
                                                  f16* __restrict__ msg) {
  int wid = threadIdx.x >> 6, lane = threadIdx.x & 63;
  int e = blockIdx.x * 4 + wid;
  if (e >= GE) return;
  float4 s = make_float4(0.f, 0.f, 0.f, 0.f);
#pragma unroll
  for (int k = 0; k < GKK; k++) {
    int nd = edges[e * GKK + k];
    float4 v = ld_h4(&h[(size_t)nd * DD + (lane << 2)]);
    s.x += v.x; s.y += v.y; s.z += v.z; s.w += v.w;
  }
  s.x *= (1.0f / GKK); s.y *= (1.0f / GKK); s.z *= (1.0f / GKK); s.w *= (1.0f / GKK);
  float4 a4 = *(const float4*)&aw[lane << 2];
  float d = s.x * a4.x + s.y * a4.y + s.z * a4.z + s.w * a4.w;
  for (int o = 32; o; o >>= 1) d += __shfl_xor(d, o);
  float a = 1.0f / (1.0f + expf(-(d + ab[0])));
  s.x *= a; s.y *= a; s.z *= a; s.w *= a;
  st_h4c(&msg[(size_t)e * DD + (lane << 2)], s);
}

// ---------- per-node: out[n] = leaky_relu( sum msg / max(cnt,1), 0.2 )  (f16 in, f32 out) ----------
__global__ __launch_bounds__(256) void k_node_att(const f16* __restrict__ msg, const int* __restrict__ off,
                                                  const int* __restrict__ csr, const int* __restrict__ cnt,
                                                  float* __restrict__ out) {
  int wid = threadIdx.x >> 6, lane = threadIdx.x & 63;
  int n = blockIdx.x * 4 + wid;
  if (n >= GN) return;
  int e0 = off[n], e1 = off[n + 1];
  float4 s = make_float4(0.f, 0.f, 0.f, 0.f);
  for (int j = e0; j < e1; j++) {
    int e = csr[j];
    float4 v = ld_h4(&msg[(size_t)e * DD + (lane << 2)]);
    s.x += v.x; s.y += v.y; s.z += v.z; s.w += v.w;
  }
  float inv = 1.0f / fmaxf((float)cnt[n], 1.0f);
  s.x *= inv; s.y *= inv; s.z *= inv; s.w *= inv;
  float4 o;
  o.x = s.x > 0.f ? s.x : 0.2f * s.x;
  o.y = s.y > 0.f ? s.y : 0.2f * s.y;
  o.z = s.z > 0.f ? s.z : 0.2f * s.z;
  o.w = s.w > 0.f ? s.w : 0.2f * s.w;
  *(float4*)&out[(size_t)n * DD + (lane << 2)] = o;
}

extern "C" void kernel_launch(void* const* d_in, const int* in_sizes, int n_in,
                              void* d_out, int out_size, void* d_ws, size_t ws_size,
                              hipStream_t stream) {
  (void)in_sizes; (void)n_in; (void)out_size; (void)ws_size;
  const float* X    = (const float*)d_in[0];
  const int*   edges= (const int*)d_in[1];
  const float* vt   = (const float*)d_in[2];
  const float* Wt   = (const float*)d_in[3];
  const float* bt   = (const float*)d_in[4];
  const float* th1  = (const float*)d_in[5];
  const float* b1   = (const float*)d_in[6];
  const float* aw1  = (const float*)d_in[7];
  const float* ab1  = (const float*)d_in[8];
  const float* th2  = (const float*)d_in[9];
  const float* b2   = (const float*)d_in[10];
  const float* aw2  = (const float*)d_in[11];
  const float* ab2  = (const float*)d_in[12];
  float* outp = (float*)d_out;

  // ---- workspace layout: byte-identical to R1/R4 (proven) ----
  char* p = (char*)d_ws;
  float* P0  = (float*)p; p += (size_t)GN * DD * 4;
  float* P1  = (float*)p; p += (size_t)GN * DD * 4;
  float* w   = (float*)p; p += (size_t)GE * 4;
  float* dvis= (float*)p; p += (size_t)GN * 4;
  float* tn  = (float*)p; p += 16 * 4;
  int* cnt   = (int*)p;   p += (size_t)GN * 4;
  int* off   = (int*)p;   p += (size_t)(GN + 1) * 4;
  int* cur   = (int*)p;   p += (size_t)GN * 4;
  int* csr   = (int*)p;   p += (size_t)GE * GKK * 4;
  p = (char*)(((uintptr_t)p + 15) & ~(uintptr_t)15);
  double* dsum = (double*)p;
  unsigned int* mbits = (unsigned int*)(p + 8);

  // f16 views: each 51.2MB f32 buffer holds two 25.6MB f16 arrays
  f16* F_P0a = (f16*)P0;
  f16* F_P0b = (f16*)((char*)P0 + (size_t)GN * DD * 2);
  f16* F_P1a = (f16*)P1;
  f16* F_P1b = (f16*)((char*)P1 + (size_t)GN * DD * 2);

  hipMemsetAsync(cnt, 0, (size_t)GN * 4, stream);
  hipMemsetAsync(cur, 0, (size_t)GN * 4, stream);
  hipMemsetAsync(dsum, 0, 16, stream);

  k_reduce<<<196, 256, 0, stream>>>(vt, GE, mbits, dsum);
  k_w<<<196, 256, 0, stream>>>(vt, mbits, dsum, Wt, bt, w, tn);
  k_count<<<3125, 256, 0, stream>>>(edges, cnt);
  k_scan<<<1, 256, 0, stream>>>(cnt, off);
  k_fill<<<3125, 256, 0, stream>>>(edges, off, cur, csr);
  k_dv<<<196, 256, 0, stream>>>(off, csr, w, dvis);
  k_h0<<<12500, 256, 0, stream>>>(X, tn, P0);

  // ---- layer 1 ----
  k_gemm<<<782, 256, 0, stream>>>(P0, th1, b1, dvis, F_P1a);            // h0(P0,f32) -> g1(P1.lo,f16)
  k_edge_msg<<<12500, 256, 0, stream>>>(F_P1a, edges, w, F_P1b);        // g1 -> m1(P1.hi)
  k_node_smooth<<<12500, 256, 0, stream>>>(F_P1b, off, csr, dvis, F_P0a); // m1 -> s1(P0.lo; h0 dead)
  k_edge_att<<<12500, 256, 0, stream>>>(F_P0a, edges, aw1, ab1, F_P1a);   // s1 -> m2(P1.lo; g1 dead)
  k_node_att<<<12500, 256, 0, stream>>>(F_P1a, off, csr, cnt, outp);      // m2 -> L1(outp,f32)

  // ---- layer 2 ----
  k_gemm<<<782, 256, 0, stream>>>(outp, th2, b2, dvis, F_P0a);          // L1 -> g2(P0.lo; s1 dead)
  k_edge_msg<<<12500, 256, 0, stream>>>(F_P0a, edges, w, F_P0b);        // g2 -> m3(P0.hi)
  k_node_smooth<<<12500, 256, 0, stream>>>(F_P0b, off, csr, dvis, F_P1a); // m3 -> s2(P1.lo; m2 dead)
  k_edge_att<<<12500, 256, 0, stream>>>(F_P1a, edges, aw2, ab2, F_P1b);   // s2 -> m4(P1.hi; m1 dead)
  k_node_att<<<12500, 256, 0, stream>>>(F_P1b, off, csr, cnt, outp);      // m4 -> out(f32; L1 dead)
}

// Round 6
// 875.118 us; speedup vs baseline: 1.5543x; 1.3014x over previous
//
#include <hip/hip_runtime.h>
#include <stdint.h>

#define GN 50000
#define GE 50000
#define GKK 16
#define DD 256
#define INDIM 240

typedef _Float16 f16;
typedef _Float16 half4 __attribute__((ext_vector_type(4)));
typedef _Float16 half8 __attribute__((ext_vector_type(8)));
typedef float f32x4 __attribute__((ext_vector_type(4)));

__device__ inline float4 ld_h4(const f16* p) {
  half4 v = *(const half4*)p;
  return make_float4((float)v.x, (float)v.y, (float)v.z, (float)v.w);
}
// clamped store: insurance against f16 overflow -> inf -> NaN
__device__ inline void st_h4c(f16* p, float4 v) {
  half4 h;
  h.x = (f16)fminf(fmaxf(v.x, -60000.f), 60000.f);
  h.y = (f16)fminf(fmaxf(v.y, -60000.f), 60000.f);
  h.z = (f16)fminf(fmaxf(v.z, -60000.f), 60000.f);
  h.w = (f16)fminf(fmaxf(v.w, -60000.f), 60000.f);
  *(half4*)p = h;
}
__device__ inline f16 h_clamp(float v) {
  return (f16)fminf(fmaxf(v, -60000.f), 60000.f);
}

// ---------- scalar reductions ----------
__global__ __launch_bounds__(256) void k_reduce(const float* __restrict__ t, int n,
                                                unsigned int* maxbits, double* sum) {
  int i0 = blockIdx.x * blockDim.x + threadIdx.x;
  int stride = gridDim.x * blockDim.x;
  float m = 0.f; double s = 0.0;
  for (int i = i0; i < n; i += stride) { float v = t[i]; m = fmaxf(m, v); s += (double)v; }
  for (int o = 32; o; o >>= 1) { m = fmaxf(m, __shfl_xor(m, o)); s += __shfl_xor(s, o); }
  if ((threadIdx.x & 63) == 0) { atomicMax(maxbits, __float_as_uint(m)); atomicAdd(sum, s); }
}

// ---------- w[e], tnode ----------
__global__ __launch_bounds__(256) void k_w(const float* __restrict__ t,
                                           const unsigned int* maxbits, const double* sum,
                                           const float* __restrict__ Wt, const float* __restrict__ bt,
                                           float* __restrict__ w, float* __restrict__ tn) {
  int i = blockIdx.x * blockDim.x + threadIdx.x;
  float maxt = __uint_as_float(*maxbits);
  if (i < GE) w[i] = expf((t[i] - maxt) * (1.0f / 365.0f));
  if (blockIdx.x == 0 && threadIdx.x < 16) {
    float mean = (float)(*sum / (double)GE);
    tn[threadIdx.x] = mean * Wt[threadIdx.x] + bt[threadIdx.x];
  }
}

// ---------- CSR build ----------
__global__ __launch_bounds__(256) void k_count(const int* __restrict__ edges, int* __restrict__ cnt) {
  int i = blockIdx.x * 256 + threadIdx.x;
  if (i < GE * GKK) atomicAdd(&cnt[edges[i]], 1);
}

__global__ __launch_bounds__(256) void k_scan(const int* __restrict__ cnt, int* __restrict__ off) {
  __shared__ int part[256];
  int t = threadIdx.x;
  const int chunk = (GN + 255) / 256;
  int beg = t * chunk, end = beg + chunk; if (end > GN) end = GN; if (beg > GN) beg = GN;
  int s = 0;
  for (int i = beg; i < end; i++) s += cnt[i];
  part[t] = s; __syncthreads();
  for (int d = 1; d < 256; d <<= 1) {
    int v = (t >= d) ? part[t - d] : 0;
    __syncthreads();
    part[t] += v;
    __syncthreads();
  }
  int base = (t == 0) ? 0 : part[t - 1];
  for (int i = beg; i < end; i++) { off[i] = base; base += cnt[i]; }
  if (t == 255) off[GN] = base;
}

__global__ __launch_bounds__(256) void k_fill(const int* __restrict__ edges, const int* __restrict__ off,
                                              int* __restrict__ cur, int* __restrict__ csr) {
  int i = blockIdx.x * 256 + threadIdx.x;
  if (i < GE * GKK) {
    int n = edges[i];
    int p = atomicAdd(&cur[n], 1);
    csr[off[n] + p] = i >> 4;  // edge id (K=16)
  }
}

// ---------- dv_isqrt ----------
__global__ __launch_bounds__(256) void k_dv(const int* __restrict__ off, const int* __restrict__ csr,
                                            const float* __restrict__ w, float* __restrict__ dvis) {
  int n = blockIdx.x * 256 + threadIdx.x;
  if (n >= GN) return;
  float dv = 0.f;
  int e0 = off[n], e1 = off[n + 1];
  for (int j = e0; j < e1; j++) dv += w[csr[j]];
  dvis[n] = dv > 0.f ? 1.0f / sqrtf(fmaxf(dv, 1e-12f)) : 0.f;
}

// ---------- h0 = concat(X, tnode) -> f16 ----------
__global__ __launch_bounds__(256) void k_h0(const float* __restrict__ X, const float* __restrict__ tn,
                                            f16* __restrict__ h) {
  int wid = threadIdx.x >> 6, lane = threadIdx.x & 63;
  int n = blockIdx.x * 4 + wid;
  if (n >= GN) return;
  float4 v;
  if (lane < 60) v = *(const float4*)&X[(size_t)n * INDIM + (lane << 2)];
  else           v = *(const float4*)&tn[(lane - 60) << 2];
  st_h4c(&h[(size_t)n * DD + (lane << 2)], v);
}

// ---------- W[k][n] f32 -> BT[n][k] f16 (32x32 tiles) ----------
__global__ __launch_bounds__(256) void k_trans_h(const float* __restrict__ W, f16* __restrict__ BT) {
  __shared__ float tile[32][33];
  int bx = blockIdx.x & 7;   // n-tile
  int by = blockIdx.x >> 3;  // k-tile
  int tx = threadIdx.x & 31, ty = threadIdx.x >> 5;  // 32 x 8
#pragma unroll
  for (int i = 0; i < 4; i++) {
    int k = by * 32 + ty + i * 8;
    tile[ty + i * 8][tx] = W[(size_t)k * DD + bx * 32 + tx];
  }
  __syncthreads();
#pragma unroll
  for (int i = 0; i < 4; i++) {
    int n = bx * 32 + ty + i * 8;
    BT[(size_t)n * DD + by * 32 + tx] = (f16)tile[tx][ty + i * 8];
  }
}

// ---------- MFMA GEMM: out[r,:] = (A[r,:] @ W + bias) * dvis[r], f16 in/out ----------
// Block: 64 rows x 256 cols; 4 waves, each 64x64; mfma_f32_16x16x32_f16.
__global__ __launch_bounds__(256) void k_gemm_mfma(const f16* __restrict__ A,
                                                   const f16* __restrict__ BT,
                                                   const float* __restrict__ bias,
                                                   const float* __restrict__ dvis,
                                                   f16* __restrict__ out) {
  int t = threadIdx.x;
  int lane = t & 63;
  int wv = t >> 6;
  int row0 = blockIdx.x * 64;
  int col0 = wv * 64;
  int lr = lane & 15;   // A row-in-tile / B col-in-tile / C col-in-tile
  int kg = lane >> 4;   // k-group

  f32x4 acc[4][4];
#pragma unroll
  for (int m = 0; m < 4; m++)
#pragma unroll
    for (int n = 0; n < 4; n++) acc[m][n] = (f32x4)(0.f);

  for (int k0 = 0; k0 < DD; k0 += 32) {
    half8 a[4], b[4];
#pragma unroll
    for (int m = 0; m < 4; m++) {
      int r = row0 + m * 16 + lr;
      r = r < GN ? r : GN - 1;                       // clamp: valid mem, rows>=GN discarded
      a[m] = *(const half8*)&A[(size_t)r * DD + k0 + kg * 8];
    }
#pragma unroll
    for (int n = 0; n < 4; n++) {
      int c = col0 + n * 16 + lr;
      b[n] = *(const half8*)&BT[(size_t)c * DD + k0 + kg * 8];
    }
#pragma unroll
    for (int m = 0; m < 4; m++)
#pragma unroll
      for (int n = 0; n < 4; n++)
        acc[m][n] = __builtin_amdgcn_mfma_f32_16x16x32_f16(a[m], b[n], acc[m][n], 0, 0, 0);
  }

#pragma unroll
  for (int m = 0; m < 4; m++) {
#pragma unroll
    for (int r = 0; r < 4; r++) {
      int row = row0 + m * 16 + kg * 4 + r;
      if (row < GN) {
        float s = dvis[row];
#pragma unroll
        for (int n = 0; n < 4; n++) {
          int c = col0 + n * 16 + lr;
          out[(size_t)row * DD + c] = h_clamp((acc[m][n][r] + bias[c]) * s);
        }
      }
    }
  }
}

// ---------- per-edge: msg[e] = w[e] * mean_k xs[edges[e,k]] ----------
__global__ __launch_bounds__(256) void k_edge_msg(const f16* __restrict__ xs, const int* __restrict__ edges,
                                                  const float* __restrict__ w, f16* __restrict__ msg) {
  int wid = threadIdx.x >> 6, lane = threadIdx.x & 63;
  int e = blockIdx.x * 4 + wid;
  if (e >= GE) return;
  float4 s = make_float4(0.f, 0.f, 0.f, 0.f);
#pragma unroll
  for (int k = 0; k < GKK; k++) {
    int nd = edges[e * GKK + k];
    float4 v = ld_h4(&xs[(size_t)nd * DD + (lane << 2)]);
    s.x += v.x; s.y += v.y; s.z += v.z; s.w += v.w;
  }
  float f = w[e] * (1.0f / GKK);
  s.x *= f; s.y *= f; s.z *= f; s.w *= f;
  st_h4c(&msg[(size_t)e * DD + (lane << 2)], s);
}

// ---------- per-node: h[n] = dvis[n] * sum msg[e] ----------
__global__ __launch_bounds__(256) void k_node_smooth(const f16* __restrict__ msg, const int* __restrict__ off,
                                                     const int* __restrict__ csr, const float* __restrict__ dvis,
                                                     f16* __restrict__ out) {
  int wid = threadIdx.x >> 6, lane = threadIdx.x & 63;
  int n = blockIdx.x * 4 + wid;
  if (n >= GN) return;
  int e0 = off[n], e1 = off[n + 1];
  float4 s = make_float4(0.f, 0.f, 0.f, 0.f);
  for (int j = e0; j < e1; j++) {
    int e = csr[j];
    float4 v = ld_h4(&msg[(size_t)e * DD + (lane << 2)]);
    s.x += v.x; s.y += v.y; s.z += v.z; s.w += v.w;
  }
  float sc = dvis[n];
  s.x *= sc; s.y *= sc; s.z *= sc; s.w *= sc;
  st_h4c(&out[(size_t)n * DD + (lane << 2)], s);
}

// ---------- per-edge attention ----------
__global__ __launch_bounds__(256) void k_edge_att(const f16* __restrict__ h, const int* __restrict__ edges,
                                                  const float* __restrict__ aw, const float* __restrict__ ab,
                                                  f16* __restrict__ msg) {
  int wid = threadIdx.x >> 6, lane = threadIdx.x & 63;
  int e = blockIdx.x * 4 + wid;
  if (e >= GE) return;
  float4 s = make_float4(0.f, 0.f, 0.f, 0.f);
#pragma unroll
  for (int k = 0; k < GKK; k++) {
    int nd = edges[e * GKK + k];
    float4 v = ld_h4(&h[(size_t)nd * DD + (lane << 2)]);
    s.x += v.x; s.y += v.y; s.z += v.z; s.w += v.w;
  }
  s.x *= (1.0f / GKK); s.y *= (1.0f / GKK); s.z *= (1.0f / GKK); s.w *= (1.0f / GKK);
  float4 a4 = *(const float4*)&aw[lane << 2];
  float d = s.x * a4.x + s.y * a4.y + s.z * a4.z + s.w * a4.w;
  for (int o = 32; o; o >>= 1) d += __shfl_xor(d, o);
  float a = 1.0f / (1.0f + expf(-(d + ab[0])));
  s.x *= a; s.y *= a; s.z *= a; s.w *= a;
  st_h4c(&msg[(size_t)e * DD + (lane << 2)], s);
}

// ---------- per-node attention aggregate, f16 out (intermediate layer) ----------
__global__ __launch_bounds__(256) void k_node_att_h(const f16* __restrict__ msg, const int* __restrict__ off,
                                                    const int* __restrict__ csr, const int* __restrict__ cnt,
                                                    f16* __restrict__ out) {
  int wid = threadIdx.x >> 6, lane = threadIdx.x & 63;
  int n = blockIdx.x * 4 + wid;
  if (n >= GN) return;
  int e0 = off[n], e1 = off[n + 1];
  float4 s = make_float4(0.f, 0.f, 0.f, 0.f);
  for (int j = e0; j < e1; j++) {
    int e = csr[j];
    float4 v = ld_h4(&msg[(size_t)e * DD + (lane << 2)]);
    s.x += v.x; s.y += v.y; s.z += v.z; s.w += v.w;
  }
  float inv = 1.0f / fmaxf((float)cnt[n], 1.0f);
  s.x *= inv; s.y *= inv; s.z *= inv; s.w *= inv;
  float4 o;
  o.x = s.x > 0.f ? s.x : 0.2f * s.x;
  o.y = s.y > 0.f ? s.y : 0.2f * s.y;
  o.z = s.z > 0.f ? s.z : 0.2f * s.z;
  o.w = s.w > 0.f ? s.w : 0.2f * s.w;
  st_h4c(&out[(size_t)n * DD + (lane << 2)], o);
}

// ---------- per-node attention aggregate, f32 out (final) ----------
__global__ __launch_bounds__(256) void k_node_att_f(const f16* __restrict__ msg, const int* __restrict__ off,
                                                    const int* __restrict__ csr, const int* __restrict__ cnt,
                                                    float* __restrict__ out) {
  int wid = threadIdx.x >> 6, lane = threadIdx.x & 63;
  int n = blockIdx.x * 4 + wid;
  if (n >= GN) return;
  int e0 = off[n], e1 = off[n + 1];
  float4 s = make_float4(0.f, 0.f, 0.f, 0.f);
  for (int j = e0; j < e1; j++) {
    int e = csr[j];
    float4 v = ld_h4(&msg[(size_t)e * DD + (lane << 2)]);
    s.x += v.x; s.y += v.y; s.z += v.z; s.w += v.w;
  }
  float inv = 1.0f / fmaxf((float)cnt[n], 1.0f);
  s.x *= inv; s.y *= inv; s.z *= inv; s.w *= inv;
  float4 o;
  o.x = s.x > 0.f ? s.x : 0.2f * s.x;
  o.y = s.y > 0.f ? s.y : 0.2f * s.y;
  o.z = s.z > 0.f ? s.z : 0.2f * s.z;
  o.w = s.w > 0.f ? s.w : 0.2f * s.w;
  *(float4*)&out[(size_t)n * DD + (lane << 2)] = o;
}

extern "C" void kernel_launch(void* const* d_in, const int* in_sizes, int n_in,
                              void* d_out, int out_size, void* d_ws, size_t ws_size,
                              hipStream_t stream) {
  (void)in_sizes; (void)n_in; (void)out_size; (void)ws_size;
  const float* X    = (const float*)d_in[0];
  const int*   edges= (const int*)d_in[1];
  const float* vt   = (const float*)d_in[2];
  const float* Wt   = (const float*)d_in[3];
  const float* bt   = (const float*)d_in[4];
  const float* th1  = (const float*)d_in[5];
  const float* b1   = (const float*)d_in[6];
  const float* aw1  = (const float*)d_in[7];
  const float* ab1  = (const float*)d_in[8];
  const float* th2  = (const float*)d_in[9];
  const float* b2   = (const float*)d_in[10];
  const float* aw2  = (const float*)d_in[11];
  const float* ab2  = (const float*)d_in[12];
  float* outp = (float*)d_out;

  // ---- workspace layout (same base as proven R1/R4/R5; BT appended) ----
  char* p = (char*)d_ws;
  float* P0  = (float*)p; p += (size_t)GN * DD * 4;
  float* P1  = (float*)p; p += (size_t)GN * DD * 4;
  float* w   = (float*)p; p += (size_t)GE * 4;
  float* dvis= (float*)p; p += (size_t)GN * 4;
  float* tn  = (float*)p; p += 16 * 4;
  int* cnt   = (int*)p;   p += (size_t)GN * 4;
  int* off   = (int*)p;   p += (size_t)(GN + 1) * 4;
  int* cur   = (int*)p;   p += (size_t)GN * 4;
  int* csr   = (int*)p;   p += (size_t)GE * GKK * 4;
  p = (char*)(((uintptr_t)p + 15) & ~(uintptr_t)15);
  double* dsum = (double*)p;
  unsigned int* mbits = (unsigned int*)(p + 8);
  p += 16;
  f16* BT1 = (f16*)p; p += (size_t)DD * DD * 2;   // 128 KB
  f16* BT2 = (f16*)p; p += (size_t)DD * DD * 2;   // 128 KB

  // f16 slots: each 51.2MB f32 buffer = two 25.6MB f16 arrays
  f16* SA = (f16*)P0;
  f16* SB = (f16*)((char*)P0 + (size_t)GN * DD * 2);
  f16* SC = (f16*)P1;
  f16* SD = (f16*)((char*)P1 + (size_t)GN * DD * 2);

  hipMemsetAsync(cnt, 0, (size_t)GN * 4, stream);
  hipMemsetAsync(cur, 0, (size_t)GN * 4, stream);
  hipMemsetAsync(dsum, 0, 16, stream);

  k_reduce<<<196, 256, 0, stream>>>(vt, GE, mbits, dsum);
  k_w<<<196, 256, 0, stream>>>(vt, mbits, dsum, Wt, bt, w, tn);
  k_count<<<3125, 256, 0, stream>>>(edges, cnt);
  k_scan<<<1, 256, 0, stream>>>(cnt, off);
  k_fill<<<3125, 256, 0, stream>>>(edges, off, cur, csr);
  k_dv<<<196, 256, 0, stream>>>(off, csr, w, dvis);
  k_trans_h<<<64, 256, 0, stream>>>(th1, BT1);
  k_trans_h<<<64, 256, 0, stream>>>(th2, BT2);
  k_h0<<<12500, 256, 0, stream>>>(X, tn, SA);

  // ---- layer 1 ----
  k_gemm_mfma<<<782, 256, 0, stream>>>(SA, BT1, b1, dvis, SC);          // h0(A) -> g1(C)
  k_edge_msg<<<12500, 256, 0, stream>>>(SC, edges, w, SD);              // g1 -> m1(D)
  k_node_smooth<<<12500, 256, 0, stream>>>(SD, off, csr, dvis, SB);     // m1 -> s1(B)
  k_edge_att<<<12500, 256, 0, stream>>>(SB, edges, aw1, ab1, SC);       // s1 -> m2(C; g1 dead)
  k_node_att_h<<<12500, 256, 0, stream>>>(SC, off, csr, cnt, SA);       // m2 -> L1(A; h0 dead)

  // ---- layer 2 ----
  k_gemm_mfma<<<782, 256, 0, stream>>>(SA, BT2, b2, dvis, SB);          // L1 -> g2(B; s1 dead)
  k_edge_msg<<<12500, 256, 0, stream>>>(SB, edges, w, SC);              // g2 -> m3(C; m2 dead)
  k_node_smooth<<<12500, 256, 0, stream>>>(SC, off, csr, dvis, SD);     // m3 -> s2(D; m1 dead)
  k_edge_att<<<12500, 256, 0, stream>>>(SD, edges, aw2, ab2, SC);       // s2 -> m4(C; m3 dead)
  k_node_att_f<<<12500, 256, 0, stream>>>(SC, off, csr, cnt, outp);     // m4 -> out (f32)
}